// Round 7
// baseline (110.549 us; speedup 1.0000x reference)
//
#include <hip/hip_runtime.h>

#define NN 4096   // H*W
#define CC 256    // channels
#define DQ 32     // d_qk
#define NB 4      // batch

typedef float        f32x4  __attribute__((ext_vector_type(4)));
typedef float        f32x16 __attribute__((ext_vector_type(16)));
typedef short        s16x4  __attribute__((ext_vector_type(4)));
typedef short        s16x8  __attribute__((ext_vector_type(8)));
typedef unsigned int u32x2  __attribute__((ext_vector_type(2)));
typedef unsigned int u32x4  __attribute__((ext_vector_type(4)));

// float -> bf16 bits, round-to-nearest-even
__device__ __forceinline__ unsigned short f2bf(float f) {
  unsigned u = __builtin_bit_cast(unsigned, f);
  u += 0x7fffu + ((u >> 16) & 1u);
  return (unsigned short)(u >> 16);
}

__device__ __forceinline__ f32x4 mfma16(s16x4 a, s16x4 b, f32x4 c) {
  return __builtin_amdgcn_mfma_f32_16x16x16bf16_1k(a, b, c, 0, 0, 0);
}
__device__ __forceinline__ f32x16 mfma32b(s16x8 a, s16x8 b, f32x16 c) {
  return __builtin_amdgcn_mfma_f32_32x32x16_bf16(a, b, c, 0, 0, 0);
}

__device__ __forceinline__ s16x4 lo4(u32x4 r) { u32x2 t = {r[0], r[1]}; return __builtin_bit_cast(s16x4, t); }
__device__ __forceinline__ s16x4 hi4(u32x4 r) { u32x2 t = {r[2], r[3]}; return __builtin_bit_cast(s16x4, t); }
__device__ __forceinline__ s16x8 bc8(u32x4 r) { return __builtin_bit_cast(s16x8, r); }

#define XLS 264   // proj LDS row stride (256 + 8 pad)

// ---------------- Kernel A: fused QKV projection ----------------
// QT: [B][N][32] bf16 row-contiguous.
// KT: LANE-ORDERED [B][jt=128][kh=2][lane=64][8] bf16:
//     KT[b][jt][kh][(j&31)+32*g2][e] = K[j][d = kh*16 + 8*g2 + e]
//     -> each attn K-frag load is one fully-coalesced 1KB dwordx4.
// Vm: LANE-ORDERED [B][jt=128][cq=8][kh=2][lane=64][8] bf16:
//     Vm[b][jt][cq][kh][(c&31)+32*g2][e] = V[c][j], with the R4-verified
//     bijection kh=(j32>>4), g2=(j32>>2)&1, e=(j32&3)|(((j32>>3)&1)<<2)
//     so A k-slots line up with P's C->B register mapping.
__global__ __launch_bounds__(256)
void proj_kernel(const float* __restrict__ x,
                 const float* __restrict__ Wq, const float* __restrict__ bq,
                 const float* __restrict__ Wk, const float* __restrict__ bk,
                 const float* __restrict__ Wv, const float* __restrict__ bv,
                 unsigned short* __restrict__ QT,
                 unsigned short* __restrict__ KT,
                 unsigned short* __restrict__ Vm) {
  __shared__ unsigned short Xl[64 * XLS];
  const int tid = threadIdx.x;
  const int b   = blockIdx.y;
  const int n0  = blockIdx.x * 64;

  {
    const int n4 = (tid & 15) * 4;
    int c = tid >> 4;
    const float* xp = x + (size_t)(b * CC + c) * NN + n0 + n4;
    #pragma unroll
    for (int it = 0; it < 16; ++it) {
      f32x4 v = *reinterpret_cast<const f32x4*>(xp);
      #pragma unroll
      for (int e = 0; e < 4; ++e)
        Xl[(n4 + e) * XLS + c] = f2bf(v[e]);
      c += 16; xp += (size_t)16 * NN;
    }
  }
  __syncthreads();

  const int wave = tid >> 6;
  const int lane = tid & 63;
  const int l16  = lane & 15;
  const int g    = lane >> 4;
  const float qscale = 0.0901684400555602f;  // log2(e)/16

  const float* wrowp[5];
  float wsc[5];
  #pragma unroll
  for (int rt = 0; rt < 5; ++rt) {
    const int R0 = (wave * 5 + rt) * 16;
    const int R  = R0 + l16;
    if (R0 < 32)      { wrowp[rt] = Wq + R * CC;        wsc[rt] = qscale; }
    else if (R0 < 64) { wrowp[rt] = Wk + (R - 32) * CC; wsc[rt] = 1.0f; }
    else              { wrowp[rt] = Wv + (R - 64) * CC; wsc[rt] = 1.0f; }
  }

  f32x4 acc[5][4];
  #pragma unroll
  for (int rt = 0; rt < 5; ++rt)
    #pragma unroll
    for (int nt = 0; nt < 4; ++nt) acc[rt][nt] = (f32x4){0.f, 0.f, 0.f, 0.f};

  for (int k0 = 0; k0 < CC; k0 += 32) {
    s16x4 xb[4][2];
    #pragma unroll
    for (int nt = 0; nt < 4; ++nt) {
      const unsigned short* p = &Xl[(l16 + 16 * nt) * XLS + k0 + 8 * g];
      u32x4 raw = *reinterpret_cast<const u32x4*>(p);
      xb[nt][0] = lo4(raw);
      xb[nt][1] = hi4(raw);
    }
    #pragma unroll
    for (int rt = 0; rt < 5; ++rt) {
      const float* wp = wrowp[rt] + k0 + 8 * g;
      f32x4 w0 = *reinterpret_cast<const f32x4*>(wp);
      f32x4 w1 = *reinterpret_cast<const f32x4*>(wp + 4);
      const float sc = wsc[rt];
      s16x4 wa0, wa1;
      #pragma unroll
      for (int e = 0; e < 4; ++e) {
        wa0[e] = (short)f2bf(w0[e] * sc);
        wa1[e] = (short)f2bf(w1[e] * sc);
      }
      #pragma unroll
      for (int nt = 0; nt < 4; ++nt) {
        acc[rt][nt] = mfma16(wa0, xb[nt][0], acc[rt][nt]);
        acc[rt][nt] = mfma16(wa1, xb[nt][1], acc[rt][nt]);
      }
    }
  }

  #pragma unroll
  for (int rt = 0; rt < 5; ++rt) {
    const int R0 = (wave * 5 + rt) * 16;
    float bias_r[4];
    {
      const float* bp; float bsc;
      if (R0 < 32)      { bp = bq + R0;      bsc = qscale; }
      else if (R0 < 64) { bp = bk + R0 - 32; bsc = 1.0f; }
      else              { bp = bv + R0 - 64; bsc = 1.0f; }
      #pragma unroll
      for (int r = 0; r < 4; ++r) bias_r[r] = bp[4 * g + r] * bsc;
    }
    #pragma unroll
    for (int nt = 0; nt < 4; ++nt) {
      const int n = n0 + nt * 16 + l16;
      float v0 = acc[rt][nt][0] + bias_r[0];
      float v1 = acc[rt][nt][1] + bias_r[1];
      float v2 = acc[rt][nt][2] + bias_r[2];
      float v3 = acc[rt][nt][3] + bias_r[3];
      if (R0 < 32) {
        u32x2 pk = { (unsigned)f2bf(v0) | ((unsigned)f2bf(v1) << 16),
                     (unsigned)f2bf(v2) | ((unsigned)f2bf(v3) << 16) };
        unsigned short* dst = QT + ((size_t)b * NN + n) * DQ + R0 + 4 * g;
        *reinterpret_cast<u32x2*>(dst) = pk;
      } else if (R0 < 64) {
        // K lane-ordered: d0..d0+3 are 4 consecutive elems of one lane's 16B
        const int d0     = R0 - 32 + 4 * g;
        const int kh     = d0 >> 4;
        const int g2v    = (d0 >> 3) & 1;
        const int e0     = d0 & 7;
        const int jt     = n >> 5;
        const int lane_t = (n & 31) + 32 * g2v;
        u32x2 pk = { (unsigned)f2bf(v0) | ((unsigned)f2bf(v1) << 16),
                     (unsigned)f2bf(v2) | ((unsigned)f2bf(v3) << 16) };
        unsigned short* kd = KT + (((size_t)(b * 128 + jt) * 2 + kh) * 64 + lane_t) * 8 + e0;
        *reinterpret_cast<u32x2*>(kd) = pk;
      } else {
        // V lane-ordered: rows c0..c0+3 -> 4 lanes, same elem slot e
        const int c0  = R0 - 64 + 4 * g;
        const int cq  = c0 >> 5;
        const int cl  = c0 & 31;
        const int jt  = (n0 + nt * 16) >> 5;
        const int kh  = nt & 1;                     // j32>>4
        const int g2v = (l16 >> 2) & 1;
        const int e   = (l16 & 3) | (((l16 >> 3) & 1) << 2);
        unsigned short* vd = Vm
          + ((((size_t)(b * 128 + jt) * 8 + cq) * 2 + kh) * 64 + (cl + 32 * g2v)) * 8 + e;
        vd[0]  = f2bf(v0);
        vd[8]  = f2bf(v1);
        vd[16] = f2bf(v2);
        vd[24] = f2bf(v3);
      }
    }
  }
}

// ---------------- Kernel B: flash attention, LDS-free main loop ----------------
// 8 waves = 2 j-halves (jq) x 4 c-slices (cs, 64 ch). Each wave: 64 q rows
// (both strips, V/K frags shared in regs), 64 tiles of 32 j. All operands are
// fully-coalesced 1KB global loads from L2-resident lane-ordered layouts.
// No LDS, no barriers in the loop; one __syncthreads for the jq merge.

#define SM16(SS, L, P0, P1) { \
  const float p0=exp2f(SS[0]),  p1=exp2f(SS[1]),  p2=exp2f(SS[2]),  p3=exp2f(SS[3]); \
  const float p4=exp2f(SS[4]),  p5=exp2f(SS[5]),  p6=exp2f(SS[6]),  p7=exp2f(SS[7]); \
  const float p8=exp2f(SS[8]),  p9=exp2f(SS[9]),  pa=exp2f(SS[10]), pb=exp2f(SS[11]); \
  const float pc=exp2f(SS[12]), pd=exp2f(SS[13]), pe=exp2f(SS[14]), pf=exp2f(SS[15]); \
  L += (((p0+p1)+(p2+p3)) + ((p4+p5)+(p6+p7))) + (((p8+p9)+(pa+pb)) + ((pc+pd)+(pe+pf))); \
  unsigned q0,q1,q2,q3,q4,q5,q6,q7; \
  asm("v_cvt_pk_bf16_f32 %0, %1, %2" : "=v"(q0) : "v"(p0), "v"(p1)); \
  asm("v_cvt_pk_bf16_f32 %0, %1, %2" : "=v"(q1) : "v"(p2), "v"(p3)); \
  asm("v_cvt_pk_bf16_f32 %0, %1, %2" : "=v"(q2) : "v"(p4), "v"(p5)); \
  asm("v_cvt_pk_bf16_f32 %0, %1, %2" : "=v"(q3) : "v"(p6), "v"(p7)); \
  asm("v_cvt_pk_bf16_f32 %0, %1, %2" : "=v"(q4) : "v"(p8), "v"(p9)); \
  asm("v_cvt_pk_bf16_f32 %0, %1, %2" : "=v"(q5) : "v"(pa), "v"(pb)); \
  asm("v_cvt_pk_bf16_f32 %0, %1, %2" : "=v"(q6) : "v"(pc), "v"(pd)); \
  asm("v_cvt_pk_bf16_f32 %0, %1, %2" : "=v"(q7) : "v"(pe), "v"(pf)); \
  u32x4 _w0 = {q0,q1,q2,q3}, _w1 = {q4,q5,q6,q7}; \
  P0 = bc8(_w0); P1 = bc8(_w1); }

// TN = tile to prefetch into the N-set; current frags in the plain set.
#define ITER(TN, KA, KB, V00, V01, V10, V11, KAN, KBN, V00N, V01N, V10N, V11N) { \
  f32x16 ss0 = mfma32b(bc8(KA), qf00, zz16); \
  f32x16 ss1 = mfma32b(bc8(KA), qf10, zz16); \
  ss0 = mfma32b(bc8(KB), qf01, ss0); \
  ss1 = mfma32b(bc8(KB), qf11, ss1); \
  { const size_t _o = (size_t)(TN) * 1024; \
    KAN = *(const u32x4*)(Kb + _o); \
    KBN = *(const u32x4*)(Kb + _o + 512); } \
  { const size_t _o = (size_t)(TN) * 8192; \
    V00N = *(const u32x4*)(Vb + _o); \
    V01N = *(const u32x4*)(Vb + _o + 512); \
    V10N = *(const u32x4*)(Vb + _o + 1024); \
    V11N = *(const u32x4*)(Vb + _o + 1536); } \
  s16x8 P00, P01, P10, P11; \
  SM16(ss0, l0, P00, P01); \
  SM16(ss1, l1, P10, P11); \
  o00 = mfma32b(bc8(V00), P00, o00); \
  o00 = mfma32b(bc8(V01), P01, o00); \
  o01 = mfma32b(bc8(V10), P00, o01); \
  o01 = mfma32b(bc8(V11), P01, o01); \
  o10 = mfma32b(bc8(V00), P10, o10); \
  o10 = mfma32b(bc8(V01), P11, o10); \
  o11 = mfma32b(bc8(V10), P10, o11); \
  o11 = mfma32b(bc8(V11), P11, o11); \
}

__global__ __launch_bounds__(512, 2)
void attn_kernel(const unsigned short* __restrict__ QT,
                 const unsigned short* __restrict__ KT,
                 const unsigned short* __restrict__ Vm,
                 const float* __restrict__ x,
                 const float* __restrict__ gamma,
                 float* __restrict__ out) {
  extern __shared__ float fb[];   // 16384 o-floats + 64 l-floats

  const int tid  = threadIdx.x;
  const int wave = tid >> 6;
  const int lane = tid & 63;
  const int l31  = lane & 31;
  const int g2   = lane >> 5;
  const int jq   = wave >> 2;    // j-half
  const int cs   = wave & 3;     // 64-channel slice

  // XCD swizzle: gid%8 -> XCD; one batch per XCD pair
  const int gid = blockIdx.x;
  const int rr  = gid & 7;
  const int qq  = gid >> 3;
  const int b   = rr >> 1;
  const int xt  = (qq << 1) | (rr & 1);
  const int ibase = xt * 64;
  const float gamma0 = gamma[0];

  // Q frags, both strips (B operand; scale folded)
  const unsigned short* Qb = QT + ((size_t)b * NN + ibase + l31) * DQ;
  const s16x8 qf00 = bc8(*(const u32x4*)(Qb + 8 * g2));
  const s16x8 qf01 = bc8(*(const u32x4*)(Qb + 16 + 8 * g2));
  const s16x8 qf10 = bc8(*(const u32x4*)(Qb + 32 * DQ + 8 * g2));
  const s16x8 qf11 = bc8(*(const u32x4*)(Qb + 32 * DQ + 16 + 8 * g2));

  f32x16 o00, o01, o10, o11, zz16;
  #pragma unroll
  for (int r = 0; r < 16; ++r) { o00[r] = 0.f; o01[r] = 0.f; o10[r] = 0.f; o11[r] = 0.f; zz16[r] = 0.f; }
  float l0 = 0.f, l1 = 0.f;

  // lane-folded bases (elem offsets)
  const unsigned short* Kb = KT + (size_t)(b * 128 + jq * 64) * 1024 + lane * 8;
  const unsigned short* Vb = Vm + ((size_t)(b * 128 + jq * 64) * 8 + cs * 2) * 1024 + lane * 8;

  u32x4 kAe, kBe, v00e, v01e, v10e, v11e;
  u32x4 kAo, kBo, v00o, v01o, v10o, v11o;

  // prologue: tile 0 -> E set
  kAe  = *(const u32x4*)(Kb);
  kBe  = *(const u32x4*)(Kb + 512);
  v00e = *(const u32x4*)(Vb);
  v01e = *(const u32x4*)(Vb + 512);
  v10e = *(const u32x4*)(Vb + 1024);
  v11e = *(const u32x4*)(Vb + 1536);

  #pragma unroll 1
  for (int tt = 0; tt < 32; ++tt) {
    const int t0 = 2 * tt;
    ITER(t0 + 1, kAe, kBe, v00e, v01e, v10e, v11e,
                 kAo, kBo, v00o, v01o, v10o, v11o);
    const int t2 = (t0 + 2 < 64) ? t0 + 2 : 63;
    ITER(t2, kAo, kBo, v00o, v01o, v10o, v11o,
             kAe, kBe, v00e, v01e, v10e, v11e);
  }

  // fold the two g2 halves of the denominators
  l0 += __shfl_xor(l0, 32);
  l1 += __shfl_xor(l1, 32);

  // ---- jq merge: each wave publishes strip (1-jq), finalizes strip jq ----
  f32x16 w0, w1; float lw;
  if (jq == 0) { w0 = o10; w1 = o11; lw = l1; }
  else         { w0 = o00; w1 = o01; lw = l0; }
  const int sW = 1 - jq;
  #pragma unroll
  for (int r = 0; r < 16; ++r) {
    fb[(((sW * 4 + cs) * 2 + 0) * 16 + r) * 64 + lane] = w0[r];
    fb[(((sW * 4 + cs) * 2 + 1) * 16 + r) * 64 + lane] = w1[r];
  }
  if (cs == 0 && g2 == 0) fb[16384 + sW * 32 + l31] = lw;
  __syncthreads();

  f32x16 m0v, m1v; float lme;
  if (jq == 0) { m0v = o00; m1v = o01; lme = l0; }
  else         { m0v = o10; m1v = o11; lme = l1; }
  const float ltot = lme + fb[16384 + jq * 32 + l31];
  const float ga = gamma0 / ltot;
  const int i = ibase + jq * 32 + l31;

  #pragma unroll
  for (int r = 0; r < 16; ++r) {
    const int c0r = cs * 64 + (r & 3) + 8 * (r >> 2) + 4 * g2;
    {
      const float part = fb[(((jq * 4 + cs) * 2 + 0) * 16 + r) * 64 + lane];
      const size_t adr = ((size_t)b * CC + c0r) * NN + i;
      out[adr] = ga * (m0v[r] + part) + x[adr];
    }
    {
      const float part = fb[(((jq * 4 + cs) * 2 + 1) * 16 + r) * 64 + lane];
      const size_t adr = ((size_t)b * CC + c0r + 32) * NN + i;
      out[adr] = ga * (m1v[r] + part) + x[adr];
    }
  }
}

extern "C" void kernel_launch(void* const* d_in, const int* in_sizes, int n_in,
                              void* d_out, int out_size, void* d_ws, size_t ws_size,
                              hipStream_t stream) {
  const float* x     = (const float*)d_in[0];
  const float* Wq    = (const float*)d_in[1];
  const float* bq    = (const float*)d_in[2];
  const float* Wk    = (const float*)d_in[3];
  const float* bk    = (const float*)d_in[4];
  const float* Wv    = (const float*)d_in[5];
  const float* bv    = (const float*)d_in[6];
  const float* gamma = (const float*)d_in[7];
  float* out = (float*)d_out;

  unsigned short* QT = (unsigned short*)d_ws;
  unsigned short* KT = QT + (size_t)NB * NN * DQ;
  unsigned short* Vm = KT + (size_t)NB * NN * DQ;

  const int ldsB = (16384 + 64) * 4;   // 65792 B dynamic LDS for the merge
  static bool attr_set = false;
  if (!attr_set) {
    hipFuncSetAttribute((const void*)attn_kernel,
                        hipFuncAttributeMaxDynamicSharedMemorySize, ldsB);
    attr_set = true;
  }

  dim3 gridP(64, NB), blkP(256);
  proj_kernel<<<gridP, blkP, 0, stream>>>(x, Wq, bq, Wk, bk, Wv, bv, QT, KT, Vm);
  attn_kernel<<<256, 512, ldsB, stream>>>(QT, KT, Vm, x, gamma, out);
}

// Round 9
// 80.569 us; speedup vs baseline: 1.3721x; 1.3721x over previous
//
#include <hip/hip_runtime.h>

#define NN 4096   // H*W
#define CC 256    // channels
#define DQ 32     // d_qk
#define NB 4      // batch

typedef float        f32x4  __attribute__((ext_vector_type(4)));
typedef float        f32x16 __attribute__((ext_vector_type(16)));
typedef short        s16x4  __attribute__((ext_vector_type(4)));
typedef short        s16x8  __attribute__((ext_vector_type(8)));
typedef unsigned int u32x2  __attribute__((ext_vector_type(2)));
typedef unsigned int u32x4  __attribute__((ext_vector_type(4)));

// float -> bf16 bits, round-to-nearest-even
__device__ __forceinline__ unsigned short f2bf(float f) {
  unsigned u = __builtin_bit_cast(unsigned, f);
  u += 0x7fffu + ((u >> 16) & 1u);
  return (unsigned short)(u >> 16);
}

__device__ __forceinline__ f32x4 mfma16(s16x4 a, s16x4 b, f32x4 c) {
  return __builtin_amdgcn_mfma_f32_16x16x16bf16_1k(a, b, c, 0, 0, 0);
}
__device__ __forceinline__ f32x16 mfma32b(s16x8 a, s16x8 b, f32x16 c) {
  return __builtin_amdgcn_mfma_f32_32x32x16_bf16(a, b, c, 0, 0, 0);
}

__device__ __forceinline__ s16x4 lo4(u32x4 r) { u32x2 t = {r[0], r[1]}; return __builtin_bit_cast(s16x4, t); }
__device__ __forceinline__ s16x4 hi4(u32x4 r) { u32x2 t = {r[2], r[3]}; return __builtin_bit_cast(s16x4, t); }
__device__ __forceinline__ s16x8 bc8(u32x4 r) { return __builtin_bit_cast(s16x8, r); }

// raw v_exp_f32: scores are bounded (|s|<~8), no denormal fixups needed.
__device__ __forceinline__ float fexp2(float x) {
  float r;
  asm("v_exp_f32 %0, %1" : "=v"(r) : "v"(x));
  return r;
}

#define XLS 264   // proj LDS row stride (256 + 8 pad)

// ---------------- Kernel A: fused QKV projection (unchanged, R7-verified) ----------------
// QT: [B][N][32] bf16 row-contiguous.
// KT: LANE-ORDERED [B][jt=128][kh=2][lane=64][8] bf16.
// Vm: LANE-ORDERED [B][jt=128][cq=8][kh=2][lane=64][8] bf16 (k-slot bijection).
__global__ __launch_bounds__(256)
void proj_kernel(const float* __restrict__ x,
                 const float* __restrict__ Wq, const float* __restrict__ bq,
                 const float* __restrict__ Wk, const float* __restrict__ bk,
                 const float* __restrict__ Wv, const float* __restrict__ bv,
                 unsigned short* __restrict__ QT,
                 unsigned short* __restrict__ KT,
                 unsigned short* __restrict__ Vm) {
  __shared__ unsigned short Xl[64 * XLS];
  const int tid = threadIdx.x;
  const int b   = blockIdx.y;
  const int n0  = blockIdx.x * 64;

  {
    const int n4 = (tid & 15) * 4;
    int c = tid >> 4;
    const float* xp = x + (size_t)(b * CC + c) * NN + n0 + n4;
    #pragma unroll
    for (int it = 0; it < 16; ++it) {
      f32x4 v = *reinterpret_cast<const f32x4*>(xp);
      #pragma unroll
      for (int e = 0; e < 4; ++e)
        Xl[(n4 + e) * XLS + c] = f2bf(v[e]);
      c += 16; xp += (size_t)16 * NN;
    }
  }
  __syncthreads();

  const int wave = tid >> 6;
  const int lane = tid & 63;
  const int l16  = lane & 15;
  const int g    = lane >> 4;
  const float qscale = 0.0901684400555602f;  // log2(e)/16

  const float* wrowp[5];
  float wsc[5];
  #pragma unroll
  for (int rt = 0; rt < 5; ++rt) {
    const int R0 = (wave * 5 + rt) * 16;
    const int R  = R0 + l16;
    if (R0 < 32)      { wrowp[rt] = Wq + R * CC;        wsc[rt] = qscale; }
    else if (R0 < 64) { wrowp[rt] = Wk + (R - 32) * CC; wsc[rt] = 1.0f; }
    else              { wrowp[rt] = Wv + (R - 64) * CC; wsc[rt] = 1.0f; }
  }

  f32x4 acc[5][4];
  #pragma unroll
  for (int rt = 0; rt < 5; ++rt)
    #pragma unroll
    for (int nt = 0; nt < 4; ++nt) acc[rt][nt] = (f32x4){0.f, 0.f, 0.f, 0.f};

  for (int k0 = 0; k0 < CC; k0 += 32) {
    s16x4 xb[4][2];
    #pragma unroll
    for (int nt = 0; nt < 4; ++nt) {
      const unsigned short* p = &Xl[(l16 + 16 * nt) * XLS + k0 + 8 * g];
      u32x4 raw = *reinterpret_cast<const u32x4*>(p);
      xb[nt][0] = lo4(raw);
      xb[nt][1] = hi4(raw);
    }
    #pragma unroll
    for (int rt = 0; rt < 5; ++rt) {
      const float* wp = wrowp[rt] + k0 + 8 * g;
      f32x4 w0 = *reinterpret_cast<const f32x4*>(wp);
      f32x4 w1 = *reinterpret_cast<const f32x4*>(wp + 4);
      const float sc = wsc[rt];
      s16x4 wa0, wa1;
      #pragma unroll
      for (int e = 0; e < 4; ++e) {
        wa0[e] = (short)f2bf(w0[e] * sc);
        wa1[e] = (short)f2bf(w1[e] * sc);
      }
      #pragma unroll
      for (int nt = 0; nt < 4; ++nt) {
        acc[rt][nt] = mfma16(wa0, xb[nt][0], acc[rt][nt]);
        acc[rt][nt] = mfma16(wa1, xb[nt][1], acc[rt][nt]);
      }
    }
  }

  #pragma unroll
  for (int rt = 0; rt < 5; ++rt) {
    const int R0 = (wave * 5 + rt) * 16;
    float bias_r[4];
    {
      const float* bp; float bsc;
      if (R0 < 32)      { bp = bq + R0;      bsc = qscale; }
      else if (R0 < 64) { bp = bk + R0 - 32; bsc = 1.0f; }
      else              { bp = bv + R0 - 64; bsc = 1.0f; }
      #pragma unroll
      for (int r = 0; r < 4; ++r) bias_r[r] = bp[4 * g + r] * bsc;
    }
    #pragma unroll
    for (int nt = 0; nt < 4; ++nt) {
      const int n = n0 + nt * 16 + l16;
      float v0 = acc[rt][nt][0] + bias_r[0];
      float v1 = acc[rt][nt][1] + bias_r[1];
      float v2 = acc[rt][nt][2] + bias_r[2];
      float v3 = acc[rt][nt][3] + bias_r[3];
      if (R0 < 32) {
        u32x2 pk = { (unsigned)f2bf(v0) | ((unsigned)f2bf(v1) << 16),
                     (unsigned)f2bf(v2) | ((unsigned)f2bf(v3) << 16) };
        unsigned short* dst = QT + ((size_t)b * NN + n) * DQ + R0 + 4 * g;
        *reinterpret_cast<u32x2*>(dst) = pk;
      } else if (R0 < 64) {
        const int d0     = R0 - 32 + 4 * g;
        const int kh     = d0 >> 4;
        const int g2v    = (d0 >> 3) & 1;
        const int e0     = d0 & 7;
        const int jt     = n >> 5;
        const int lane_t = (n & 31) + 32 * g2v;
        u32x2 pk = { (unsigned)f2bf(v0) | ((unsigned)f2bf(v1) << 16),
                     (unsigned)f2bf(v2) | ((unsigned)f2bf(v3) << 16) };
        unsigned short* kd = KT + (((size_t)(b * 128 + jt) * 2 + kh) * 64 + lane_t) * 8 + e0;
        *reinterpret_cast<u32x2*>(kd) = pk;
      } else {
        const int c0  = R0 - 64 + 4 * g;
        const int cq  = c0 >> 5;
        const int cl  = c0 & 31;
        const int jt  = (n0 + nt * 16) >> 5;
        const int kh  = nt & 1;
        const int g2v = (l16 >> 2) & 1;
        const int e   = (l16 & 3) | (((l16 >> 3) & 1) << 2);
        unsigned short* vd = Vm
          + ((((size_t)(b * 128 + jt) * 8 + cq) * 2 + kh) * 64 + (cl + 32 * g2v)) * 8 + e;
        vd[0]  = f2bf(v0);
        vd[8]  = f2bf(v1);
        vd[16] = f2bf(v2);
        vd[24] = f2bf(v3);
      }
    }
  }
}

// ---------------- Kernel B: flash attention, LDS-free, fast exp2, depth-2 prefetch ----------------
// 8 waves = 2 j-halves (jq) x 4 c-slices (cs). Each wave: 64 q (2 strips,
// sharing V/K frags) x 64 c x 2048 j. All operands are coalesced 1KB L2 loads.

#define SM16(SS, L, P0, P1) { \
  const float p0=fexp2(SS[0]),  p1=fexp2(SS[1]),  p2=fexp2(SS[2]),  p3=fexp2(SS[3]); \
  const float p4=fexp2(SS[4]),  p5=fexp2(SS[5]),  p6=fexp2(SS[6]),  p7=fexp2(SS[7]); \
  const float p8=fexp2(SS[8]),  p9=fexp2(SS[9]),  pa=fexp2(SS[10]), pb=fexp2(SS[11]); \
  const float pc=fexp2(SS[12]), pd=fexp2(SS[13]), pe=fexp2(SS[14]), pf=fexp2(SS[15]); \
  L += (((p0+p1)+(p2+p3)) + ((p4+p5)+(p6+p7))) + (((p8+p9)+(pa+pb)) + ((pc+pd)+(pe+pf))); \
  unsigned q0,q1,q2,q3,q4,q5,q6,q7; \
  asm("v_cvt_pk_bf16_f32 %0, %1, %2" : "=v"(q0) : "v"(p0), "v"(p1)); \
  asm("v_cvt_pk_bf16_f32 %0, %1, %2" : "=v"(q1) : "v"(p2), "v"(p3)); \
  asm("v_cvt_pk_bf16_f32 %0, %1, %2" : "=v"(q2) : "v"(p4), "v"(p5)); \
  asm("v_cvt_pk_bf16_f32 %0, %1, %2" : "=v"(q3) : "v"(p6), "v"(p7)); \
  asm("v_cvt_pk_bf16_f32 %0, %1, %2" : "=v"(q4) : "v"(p8), "v"(p9)); \
  asm("v_cvt_pk_bf16_f32 %0, %1, %2" : "=v"(q5) : "v"(pa), "v"(pb)); \
  asm("v_cvt_pk_bf16_f32 %0, %1, %2" : "=v"(q6) : "v"(pc), "v"(pd)); \
  asm("v_cvt_pk_bf16_f32 %0, %1, %2" : "=v"(q7) : "v"(pe), "v"(pf)); \
  u32x4 _w0 = {q0,q1,q2,q3}, _w1 = {q4,q5,q6,q7}; \
  P0 = bc8(_w0); P1 = bc8(_w1); }

// NOTE: one-level indirection so SET_A/B/C expand BEFORE argument binding
// (R8's compile failure: argument counting precedes argument expansion).
#define LOADSET_IMPL(T, KA, KB, V00, V01, V10, V11) { \
  { const size_t _o = (size_t)(T) * 1024; \
    KA = *(const u32x4*)(Kb + _o); \
    KB = *(const u32x4*)(Kb + _o + 512); } \
  { const size_t _o = (size_t)(T) * 8192; \
    V00 = *(const u32x4*)(Vb + _o); \
    V01 = *(const u32x4*)(Vb + _o + 512); \
    V10 = *(const u32x4*)(Vb + _o + 1024); \
    V11 = *(const u32x4*)(Vb + _o + 1536); } }
#define LOADSET(T, SET) LOADSET_IMPL(T, SET)

// compute current set; prefetch tile TN into the set freed last iteration
#define ITER_IMPL(TN, KA, KB, V00, V01, V10, V11, KAN, KBN, V00N, V01N, V10N, V11N) { \
  LOADSET_IMPL(TN, KAN, KBN, V00N, V01N, V10N, V11N); \
  f32x16 ss0 = mfma32b(bc8(KA), qf00, zz16); \
  ss0 = mfma32b(bc8(KB), qf01, ss0); \
  f32x16 ss1 = mfma32b(bc8(KA), qf10, zz16); \
  ss1 = mfma32b(bc8(KB), qf11, ss1); \
  s16x8 P00, P01, P10, P11; \
  SM16(ss0, l0, P00, P01); \
  SM16(ss1, l1, P10, P11); \
  o00 = mfma32b(bc8(V00), P00, o00); \
  o00 = mfma32b(bc8(V01), P01, o00); \
  o01 = mfma32b(bc8(V10), P00, o01); \
  o01 = mfma32b(bc8(V11), P01, o01); \
  o10 = mfma32b(bc8(V00), P10, o10); \
  o10 = mfma32b(bc8(V01), P11, o10); \
  o11 = mfma32b(bc8(V10), P10, o11); \
  o11 = mfma32b(bc8(V11), P11, o11); \
}
#define ITER(TN, SETC, SETN) ITER_IMPL(TN, SETC, SETN)

#define SET_A kA0, kB0, v000, v010, v100, v110
#define SET_B kA1, kB1, v001, v011, v101, v111
#define SET_C kA2, kB2, v002, v012, v102, v112

__global__ __launch_bounds__(512, 2)
void attn_kernel(const unsigned short* __restrict__ QT,
                 const unsigned short* __restrict__ KT,
                 const unsigned short* __restrict__ Vm,
                 const float* __restrict__ x,
                 const float* __restrict__ gamma,
                 float* __restrict__ out) {
  extern __shared__ float fb[];   // 16384 o-floats + 64 l-floats

  const int tid  = threadIdx.x;
  const int wave = tid >> 6;
  const int lane = tid & 63;
  const int l31  = lane & 31;
  const int g2   = lane >> 5;
  const int jq   = wave >> 2;    // j-half
  const int cs   = wave & 3;     // 64-channel slice

  // XCD swizzle: gid%8 -> XCD; one batch per XCD pair
  const int gid = blockIdx.x;
  const int rr  = gid & 7;
  const int qq  = gid >> 3;
  const int b   = rr >> 1;
  const int xt  = (qq << 1) | (rr & 1);
  const int ibase = xt * 64;
  const float gamma0 = gamma[0];

  const unsigned short* Qb = QT + ((size_t)b * NN + ibase + l31) * DQ;
  const s16x8 qf00 = bc8(*(const u32x4*)(Qb + 8 * g2));
  const s16x8 qf01 = bc8(*(const u32x4*)(Qb + 16 + 8 * g2));
  const s16x8 qf10 = bc8(*(const u32x4*)(Qb + 32 * DQ + 8 * g2));
  const s16x8 qf11 = bc8(*(const u32x4*)(Qb + 32 * DQ + 16 + 8 * g2));

  f32x16 o00, o01, o10, o11, zz16;
  #pragma unroll
  for (int r = 0; r < 16; ++r) { o00[r] = 0.f; o01[r] = 0.f; o10[r] = 0.f; o11[r] = 0.f; zz16[r] = 0.f; }
  float l0 = 0.f, l1 = 0.f;

  const unsigned short* Kb = KT + (size_t)(b * 128 + jq * 64) * 1024 + lane * 8;
  const unsigned short* Vb = Vm + ((size_t)(b * 128 + jq * 64) * 8 + cs * 2) * 1024 + lane * 8;

  u32x4 kA0, kB0, v000, v010, v100, v110;
  u32x4 kA1, kB1, v001, v011, v101, v111;
  u32x4 kA2, kB2, v002, v012, v102, v112;

  // prologue: t0 -> A, t1 -> B
  LOADSET(0, SET_A);
  LOADSET(1, SET_B);

  // steady state: compute t (set t%3), prefetch t+2 (set (t+2)%3, freed at t-1)
  #pragma unroll 1
  for (int tt = 0; tt < 21; ++tt) {
    const int t = 3 * tt;
    ITER(t + 2, SET_A, SET_C);
    ITER(t + 3, SET_B, SET_A);
    { const int t4 = (t + 4 < 64) ? t + 4 : 63;
      ITER(t4, SET_C, SET_B); }
  }
  ITER(63, SET_A, SET_C);   // t = 63 (63%3 == 0 -> set A)

  // fold the two g2 halves of the denominators
  l0 += __shfl_xor(l0, 32);
  l1 += __shfl_xor(l1, 32);

  // ---- jq merge: each wave publishes strip (1-jq), finalizes strip jq ----
  f32x16 w0, w1; float lw;
  if (jq == 0) { w0 = o10; w1 = o11; lw = l1; }
  else         { w0 = o00; w1 = o01; lw = l0; }
  const int sW = 1 - jq;
  #pragma unroll
  for (int r = 0; r < 16; ++r) {
    fb[(((sW * 4 + cs) * 2 + 0) * 16 + r) * 64 + lane] = w0[r];
    fb[(((sW * 4 + cs) * 2 + 1) * 16 + r) * 64 + lane] = w1[r];
  }
  if (cs == 0 && g2 == 0) fb[16384 + sW * 32 + l31] = lw;
  __syncthreads();

  f32x16 m0v, m1v; float lme;
  if (jq == 0) { m0v = o00; m1v = o01; lme = l0; }
  else         { m0v = o10; m1v = o11; lme = l1; }
  const float ltot = lme + fb[16384 + jq * 32 + l31];
  const float ga = gamma0 / ltot;
  const int i = ibase + jq * 32 + l31;

  #pragma unroll
  for (int r = 0; r < 16; ++r) {
    const int c0r = cs * 64 + (r & 3) + 8 * (r >> 2) + 4 * g2;
    {
      const float part = fb[(((jq * 4 + cs) * 2 + 0) * 16 + r) * 64 + lane];
      const size_t adr = ((size_t)b * CC + c0r) * NN + i;
      out[adr] = ga * (m0v[r] + part) + x[adr];
    }
    {
      const float part = fb[(((jq * 4 + cs) * 2 + 1) * 16 + r) * 64 + lane];
      const size_t adr = ((size_t)b * CC + c0r + 32) * NN + i;
      out[adr] = ga * (m1v[r] + part) + x[adr];
    }
  }
}

extern "C" void kernel_launch(void* const* d_in, const int* in_sizes, int n_in,
                              void* d_out, int out_size, void* d_ws, size_t ws_size,
                              hipStream_t stream) {
  const float* x     = (const float*)d_in[0];
  const float* Wq    = (const float*)d_in[1];
  const float* bq    = (const float*)d_in[2];
  const float* Wk    = (const float*)d_in[3];
  const float* bk    = (const float*)d_in[4];
  const float* Wv    = (const float*)d_in[5];
  const float* bv    = (const float*)d_in[6];
  const float* gamma = (const float*)d_in[7];
  float* out = (float*)d_out;

  unsigned short* QT = (unsigned short*)d_ws;
  unsigned short* KT = QT + (size_t)NB * NN * DQ;
  unsigned short* Vm = KT + (size_t)NB * NN * DQ;

  const int ldsB = (16384 + 64) * 4;   // 65792 B dynamic LDS for the merge
  static bool attr_set = false;
  if (!attr_set) {
    hipFuncSetAttribute((const void*)attn_kernel,
                        hipFuncAttributeMaxDynamicSharedMemorySize, ldsB);
    attr_set = true;
  }

  dim3 gridP(64, NB), blkP(256);
  proj_kernel<<<gridP, blkP, 0, stream>>>(x, Wq, bq, Wk, bk, Wv, bv, QT, KT, Vm);
  attn_kernel<<<256, 512, ldsB, stream>>>(QT, KT, Vm, x, gamma, out);
}